// Round 4
// baseline (103.688 us; speedup 1.0000x reference)
//
#include <hip/hip_runtime.h>
#include <hip/hip_bf16.h>

// PerPixelConv: out[b,c,h,w] = sum_{dy,dx} input_zp[b,c,h+dy-1,w+dx-1] * kernel[b,dy*3+dx,h,w]
// input [8,3,720,1280] f32, kernel [8,9,720,1280] f32, out [8,3,720,1280] f32.
// Memory-bound (442 MB min traffic). R3 = 83.8us (5.3 TB/s effective).
// R4: 8 px/thread (2x f32x4 per channel-row) to cut VMEM instructions/byte by
// ~2x and raise memory-level parallelism. dy-outer loop: input row segments
// loaded once per dy, kernel taps streamed NT. XCD-chunked swizzle kept
// (3600 blocks, 450/XCD = exactly one batch image per XCD).

#ifndef PPC_CONSTS
#define PPC_CONSTS
constexpr int PB = 8, PC = 3, PH = 720, PW = 1280;
constexpr int PHW = PH * PW;
constexpr int PWG = PW / 8;              // 8-px groups per row = 160
constexpr int PTOTAL = PB * PH * PWG;    // 921,600 threads
constexpr int PBLK = 256;
constexpr int PNBLK = PTOTAL / PBLK;     // 3600 blocks (exact)
constexpr int PNXCD = 8;
constexpr int PCHUNK = PNBLK / PNXCD;    // 450 (bijective: 3600 % 8 == 0)
typedef float f32x4 __attribute__((ext_vector_type(4)));
#endif

__global__ __launch_bounds__(PBLK) void PerPixelConv_kernel(
    const float* __restrict__ input,
    const float* __restrict__ kernel,
    float* __restrict__ out)
{
    // XCD-aware swizzle: XCD x gets contiguous logical chunk -> one batch image.
    int lb  = (blockIdx.x % PNXCD) * PCHUNK + blockIdx.x / PNXCD;
    int idx = lb * PBLK + threadIdx.x;

    int wg = idx % PWG;
    int h  = (idx / PWG) % PH;
    int b  = idx / (PWG * PH);
    int w0 = wg * 8;

    const float* kbase = kernel + (size_t)b * 9 * PHW + (size_t)h * PW + w0;
    const float* ibase = input + (size_t)b * PC * PHW;

    float acc[PC][8];
    #pragma unroll
    for (int c = 0; c < PC; ++c)
        #pragma unroll
        for (int j = 0; j < 8; ++j)
            acc[c][j] = 0.f;

    #pragma unroll
    for (int dy = 0; dy < 3; ++dy) {
        int row = h + dy - 1;
        if (row < 0 || row >= PH) continue;     // zero padding (vertical)

        // Input segments: x[c][i] = input[b,c,row, w0 + i - 1], i in 0..9
        float x[PC][10];
        #pragma unroll
        for (int c = 0; c < PC; ++c) {
            const float* r = ibase + (size_t)c * PHW + (size_t)row * PW + w0;
            f32x4 lo = *reinterpret_cast<const f32x4*>(r);
            f32x4 hi = *reinterpret_cast<const f32x4*>(r + 4);
            x[c][0] = (w0 > 0)      ? r[-1] : 0.f;   // left pad
            x[c][9] = (w0 + 8 < PW) ? r[8]  : 0.f;   // right pad
            #pragma unroll
            for (int i = 0; i < 4; ++i) { x[c][1 + i] = lo[i]; x[c][5 + i] = hi[i]; }
        }

        // Stream kernel taps for this dy (single-use -> nontemporal).
        #pragma unroll
        for (int dx = 0; dx < 3; ++dx) {
            const float* kp = kbase + (size_t)(dy * 3 + dx) * PHW;
            f32x4 k0 = __builtin_nontemporal_load(reinterpret_cast<const f32x4*>(kp));
            f32x4 k1 = __builtin_nontemporal_load(reinterpret_cast<const f32x4*>(kp + 4));
            #pragma unroll
            for (int c = 0; c < PC; ++c) {
                #pragma unroll
                for (int j = 0; j < 4; ++j) {
                    acc[c][j]     += x[c][j + dx]     * k0[j];
                    acc[c][4 + j] += x[c][4 + j + dx] * k1[j];
                }
            }
        }
    }

    float* obase = out + (size_t)b * PC * PHW + (size_t)h * PW + w0;
    #pragma unroll
    for (int c = 0; c < PC; ++c) {
        f32x4 o0, o1;
        #pragma unroll
        for (int j = 0; j < 4; ++j) { o0[j] = acc[c][j]; o1[j] = acc[c][4 + j]; }
        __builtin_nontemporal_store(o0, reinterpret_cast<f32x4*>(obase + (size_t)c * PHW));
        __builtin_nontemporal_store(o1, reinterpret_cast<f32x4*>(obase + (size_t)c * PHW + 4));
    }
}

extern "C" void kernel_launch(void* const* d_in, const int* in_sizes, int n_in,
                              void* d_out, int out_size, void* d_ws, size_t ws_size,
                              hipStream_t stream) {
    const float* input  = (const float*)d_in[0];
    const float* kernel = (const float*)d_in[1];
    float* out = (float*)d_out;

    PerPixelConv_kernel<<<PNBLK, PBLK, 0, stream>>>(input, kernel, out);
}

// Round 5
// 78.521 us; speedup vs baseline: 1.3205x; 1.3205x over previous
//
#include <hip/hip_runtime.h>
#include <hip/hip_bf16.h>

// PerPixelConv: out[b,c,h,w] = sum_{dy,dx} input_zp[b,c,h+dy-1,w+dx-1] * kernel[b,dy*3+dx,h,w]
// input [8,3,720,1280] f32, kernel [8,9,720,1280] f32, out [8,3,720,1280] f32.
// Memory-bound (442 MB min). R3 (4px/thread dense) = 83.8us. R4 (8px, strided
// pairs) = 103.7us REGRESSION: 32B/lane footprint with 16B loads halves
// per-instruction coalescing density -> 2x cache-line touches. Lesson: keep
// lane footprint == load width.
// R5: R3 layout + edge values via cross-lane shuffle instead of 18 scalar
// loads (neighbor pixels already live in adjacent lanes). VMEM 39 -> 30/thread.
// h is wave-uniform (320 groups/row, 64 | 320) so boundary `continue` and
// shuffles are divergence-safe.

#ifndef PPC_CONSTS
#define PPC_CONSTS
constexpr int PB = 8, PC = 3, PH = 720, PW = 1280;
constexpr int PHW = PH * PW;
constexpr int PWG = PW / 4;              // float4 groups per row = 320
constexpr int PTOTAL = PB * PH * PWG;    // 1,843,200 threads
constexpr int PBLK = 256;
constexpr int PNBLK = PTOTAL / PBLK;     // 7200 blocks (exact)
constexpr int PNXCD = 8;
constexpr int PCHUNK = PNBLK / PNXCD;    // 900 (bijective: 7200 % 8 == 0)
typedef float f32x4 __attribute__((ext_vector_type(4)));
#endif

__global__ __launch_bounds__(PBLK) void PerPixelConv_kernel(
    const float* __restrict__ input,
    const float* __restrict__ kernel,
    float* __restrict__ out)
{
    // XCD-aware chunked swizzle: XCD x handles one contiguous batch image.
    int lb  = (blockIdx.x % PNXCD) * PCHUNK + blockIdx.x / PNXCD;
    int idx = lb * PBLK + threadIdx.x;
    int lane = threadIdx.x & 63;

    int wg = idx % PWG;
    int h  = (idx / PWG) % PH;           // wave-uniform
    int b  = idx / (PWG * PH);           // wave-uniform
    int w0 = wg * 4;

    // 9 per-pixel kernel taps for these 4 pixels (single-use -> nontemporal).
    const float* kbase = kernel + (size_t)b * 9 * PHW + (size_t)h * PW + w0;
    f32x4 kv[9];
    #pragma unroll
    for (int k = 0; k < 9; ++k)
        kv[k] = __builtin_nontemporal_load(
                    reinterpret_cast<const f32x4*>(kbase + (size_t)k * PHW));

    const float* ibase = input + (size_t)b * PC * PHW;
    float*       obase = out   + (size_t)b * PC * PHW;

    // Edge-load offset: lane 0 wants r[-1] (left halo of the wave), lane 63
    // wants r[4] (right halo). Other lanes' value is unused. Clamp at image
    // borders to keep the address in-bounds; border value is replaced by 0.
    const bool leftEdge  = (w0 == 0);         // only possible for lane 0
    const bool rightEdge = (w0 + 4 == PW);    // only possible for lane 63
    const int  eoff = (lane == 0) ? (leftEdge ? 0 : -1)
                                  : (rightEdge ? 3 : 4);

    #pragma unroll
    for (int c = 0; c < PC; ++c) {
        float acc0 = 0.f, acc1 = 0.f, acc2 = 0.f, acc3 = 0.f;
        #pragma unroll
        for (int dy = 0; dy < 3; ++dy) {
            int row = h + dy - 1;
            if (row < 0 || row >= PH) continue;   // wave-uniform zero-pad skip
            const float* r = ibase + (size_t)c * PHW + (size_t)row * PW + w0;
            f32x4 mid = *reinterpret_cast<const f32x4*>(r);
            float edge = r[eoff];                 // 1 scalar load per (c,row)

            // Halo from neighbor lanes; wave-boundary lanes use `edge`.
            float x0 = __shfl_up(mid.w, 1);       // lane i <- lane i-1's w0+3
            if (lane == 0)  x0 = leftEdge  ? 0.f : edge;
            float x5 = __shfl_down(mid.x, 1);     // lane i <- lane i+1's w0
            if (lane == 63) x5 = rightEdge ? 0.f : edge;

            float x1 = mid.x, x2 = mid.y, x3 = mid.z, x4 = mid.w;

            f32x4 k0 = kv[dy * 3 + 0];
            f32x4 k1 = kv[dy * 3 + 1];
            f32x4 k2 = kv[dy * 3 + 2];
            acc0 += x0 * k0.x;  acc1 += x1 * k0.y;  acc2 += x2 * k0.z;  acc3 += x3 * k0.w;
            acc0 += x1 * k1.x;  acc1 += x2 * k1.y;  acc2 += x3 * k1.z;  acc3 += x4 * k1.w;
            acc0 += x2 * k2.x;  acc1 += x3 * k2.y;  acc2 += x4 * k2.z;  acc3 += x5 * k2.w;
        }
        f32x4 o;
        o.x = acc0; o.y = acc1; o.z = acc2; o.w = acc3;
        __builtin_nontemporal_store(
            o, reinterpret_cast<f32x4*>(obase + (size_t)c * PHW + (size_t)h * PW + w0));
    }
}

extern "C" void kernel_launch(void* const* d_in, const int* in_sizes, int n_in,
                              void* d_out, int out_size, void* d_ws, size_t ws_size,
                              hipStream_t stream) {
    const float* input  = (const float*)d_in[0];
    const float* kernel = (const float*)d_in[1];
    float* out = (float*)d_out;

    PerPixelConv_kernel<<<PNBLK, PBLK, 0, stream>>>(input, kernel, out);
}